// Round 13
// baseline (260.869 us; speedup 1.0000x reference)
//
#include <hip/hip_runtime.h>

// ---------------------------------------------------------------------------
// ConvCaps (EM routing): b=8, B=32, C=32, K=3, stride=2, Win=13, Wout=6, 3 iters
// x: (8, 544, 13, 13) f32   [pose 512ch = (q,r,o), act 32ch]
// W: (3,3,32,32,4,4) f32    [ch=(ij*32+o)][c][p][q], 512 floats per ch
// out: (8, 544, 6, 6) f32
// vote[d=p*4+r] = sum_q W[ch][c][p][q] * pose[n,q,r,o, 2x+i, 2y+j]
//
// R13 = R10 compute with SLICE-STAGED pose: LDS 29184 -> 6144 B.
// Evidence (R2/R7/R8/R10): occupancy pinned at ~2.2-2.6 blocks/CU by LDS
// (effective pool ~64KB) regardless of launch bounds. Chunk k already maps
// lanes to ij-slices {2k, 2k+1} (half = lane>>5, o = lane&31), so stage only
// those 2 slices per step (2x32x20 f = 5120 B) from posT2[n][pix][o][d]
// (contiguous 2KB per slice). sE -> per-lane rh[5] registers (coalesced
// a/D/p_hat loads). sPh -> per-step [4][64] (1024 B), drained during the
// next step's staging phase. 21 barriers, hidden by 6+ resident blocks.
// Session rules: asm packed math regressed (scheduling); natural VGPR ~60-90;
// caps below live set (256,3)/(256,5) -> spill. WRITE >> 13MB = spill guard.
// p_hat slices block-private; only D crosses blocks -> ping-pong D0/D1.
// ---------------------------------------------------------------------------

typedef float v2f __attribute__((ext_vector_type(2)));
typedef float v4f __attribute__((ext_vector_type(4)));

// workspace layout (floats)
#define OFF_PHAT 0           // 288*32*288 = 2654208   [spatial][c][slot]
#define OFF_D0   2654208     // 43264 = 8*169*32   [n][pix][o]
#define OFF_D1   2697472     // 43264
#define OFF_POST 2740736     // 692224 = 8*169*32*16   [n][pix][o][d]
#define OFF_ACTT 3432960     // 43264  [n][pix][o]
#define OFF_WT2  3476224     // 147456 = 32*288*16  [c][ch][d]
// total 3623680 floats = 14.5 MB

__device__ __forceinline__ float wred64(float v) {
#pragma unroll
  for (int m = 32; m >= 1; m >>= 1) v += __shfl_xor(v, m, 64);
  return v;
}

__device__ __forceinline__ v2f lo2(v4f a) { return __builtin_shufflevector(a, a, 0, 1); }
__device__ __forceinline__ v2f hi2(v4f a) { return __builtin_shufflevector(a, a, 2, 3); }

// One fused prep kernel (range-branched elementwise):
//   [0,692224)        pose transpose -> posT2[((n*169+pix)*32+o)*16 + d]
//   [692224,735488)   act transpose  -> actT[n][pix][o]
//   [735488,882944)   W transpose    -> Wt2[c][ch][d]
//   [882944,969472)   zero D0 and D1
__global__ __launch_bounds__(256) void prep_kernel(
    const float* __restrict__ x, const float* __restrict__ Wt,
    float* __restrict__ posT2, float* __restrict__ actT,
    float* __restrict__ Wt2, float* __restrict__ Dz) {
  int tid = blockIdx.x * 256 + threadIdx.x;   // 969472 = 3787*256
  if (tid < 692224) {
    int pix = tid % 169; int t = tid / 169;
    int o = t & 31; t >>= 5;
    int d = t & 15; int n = t >> 4;
    float v = x[((size_t)n * 544 + d * 32 + o) * 169 + pix];
    posT2[(((size_t)n * 169 + pix) * 32 + o) * 16 + d] = v;
  } else if (tid < 735488) {
    int r = tid - 692224;
    int pix = r % 169; int t = r / 169;
    int o = t & 31; int n = t >> 5;
    float v = x[(size_t)n * 91936 + 86528 + o * 169 + pix];
    actT[((size_t)n * 169 + pix) * 32 + o] = v;
  } else if (tid < 882944) {
    int r = tid - 735488;                     // 147456 = 32*288*16
    int c = r / 4608; int s = r - c * 4608;
    int ch = s >> 4, d = s & 15;
    Wt2[r] = Wt[(size_t)ch * 512 + c * 16 + d];
  } else {
    Dz[tid - 882944] = 0.f;                   // D0 then D1 (contiguous)
  }
}

// Fused EM step.
// mode 0: M(uniform Rp) + E -> p_hat, Dwrite
// mode 1: M(p_hat, Dread) + E -> p_hat, Dwrite
// mode 2: M(p_hat, Dread) -> final output
__global__ __launch_bounds__(256, 4) void em_kernel(
    const float* __restrict__ Wt2, const float* __restrict__ posT2,
    const float* __restrict__ actT, float* __restrict__ p_hat,
    const float* __restrict__ Dread, float* __restrict__ Dwrite,
    const float* __restrict__ beta_v, const float* __restrict__ beta_a,
    const float* __restrict__ lambda_, float* __restrict__ out, int mode) {
  __shared__ float sPs[2 * 32 * 20];   // 5120 B: two ij-slices, stride 20
  __shared__ float sPh[4 * 64];        // 1024 B: per-step ph for D reduce

  const int g = blockIdx.x & 7;        // c group
  const int sg = blockIdx.x >> 3;      // spatial 0..287
  const int wave = threadIdx.x >> 6;
  const int lane = threadIdx.x & 63;
  const int c = g * 4 + wave;
  const int o = lane & 31;
  const int half = lane >> 5;

  int t = sg;
  const int y = t % 6; t /= 6;
  const int xx = t % 6;
  const int n = t / 6;

  const float bvv = beta_v[0], bav = beta_a[0], lamv = lambda_[0];
  const float* wbase = Wt2 + (size_t)c * 4608;
  const float* phb = p_hat + ((size_t)sg * 32 + c) * 288;

  // ---- per-lane rhat prefetch (coalesced; overlaps first staging) ----
  float rh[5];
#pragma unroll
  for (int k = 0; k < 5; ++k) {
    const int ij = half + 2 * k;
    const bool valid = (ij < 9);
    const int ijc = valid ? ij : 0;
    const int i = ijc / 3, j = ijc - 3 * i;
    const int idx = ((n * 169 + (2 * xx + i) * 13 + (2 * y + j)) * 32) + o;
    float a = actT[idx];
    float r;
    if (mode == 0) {
      r = a * (1.0f / 1152.0f);
    } else {
      float ph = phb[valid ? (lane + 64 * k) : 0];
      r = ph * a * __builtin_amdgcn_rcpf(Dread[idx]);
    }
    rh[k] = valid ? r : 0.f;
  }

  // ---- M phase: slice-staged steps ----
  float sum_r = 0.f;
  v2f sv2[8], sq2[8];
#pragma unroll
  for (int d = 0; d < 8; ++d) { sv2[d] = 0.f; sq2[d] = 0.f; }

#pragma unroll
  for (int k = 0; k < 5; ++k) {
    __syncthreads();
    {
      const int tt = threadIdx.x;           // 256 tasks = 2 slices x 32 o x 4 q
      const int s = tt >> 7, o2 = (tt >> 2) & 31, q = tt & 3;
      const int ij = 2 * k + s;
      if (ij < 9) {
        const int i = ij / 3, j = ij - 3 * i;
        const int pix = (2 * xx + i) * 13 + (2 * y + j);
        v4f v = *(const v4f*)(posT2 +
            ((size_t)((n * 169 + pix) * 32 + o2)) * 16 + q * 4);
        *(v4f*)(sPs + (s * 32 + o2) * 20 + q * 4) = v;
      }
    }
    __syncthreads();

    const bool valid = (half + 2 * k) < 9;
    const int row = valid ? lane : 0;         // row = half*32+o = lane
    const int chm = valid ? (lane + 64 * k) : 0;

    const v4f* Pp = (const v4f*)(sPs + row * 20);
    v4f P0 = Pp[0], P1 = Pp[1], P2 = Pp[2], P3 = Pp[3];
    const v4f* Wp = (const v4f*)(wbase + chm * 16);
    v4f W0 = Wp[0], W1 = Wp[1], W2 = Wp[2], W3 = Wp[3];

    const float rhat = rh[k];
    sum_r += rhat;

    v2f PL0 = lo2(P0), PH0 = hi2(P0), PL1 = lo2(P1), PH1 = hi2(P1);
    v2f PL2 = lo2(P2), PH2 = hi2(P2), PL3 = lo2(P3), PH3 = hi2(P3);
    v2f r2 = rhat;

#pragma unroll
    for (int p = 0; p < 4; ++p) {
      v4f Wr = (p == 0) ? W0 : (p == 1) ? W1 : (p == 2) ? W2 : W3;
      v2f vlo = Wr.x * PL0 + Wr.y * PL1 + Wr.z * PL2 + Wr.w * PL3;
      v2f vhi = Wr.x * PH0 + Wr.y * PH1 + Wr.z * PH2 + Wr.w * PH3;
      v2f tlo = r2 * vlo, thi = r2 * vhi;
      sv2[p * 2 + 0] += tlo;
      sv2[p * 2 + 1] += thi;
      sq2[p * 2 + 0] += tlo * vlo;
      sq2[p * 2 + 1] += thi * vhi;
    }
  }

  sum_r = wred64(sum_r);
  const float inv_sr = 1.0f / sum_r;
  float mu[16];
  float lsum = 0.f;
#pragma unroll
  for (int d = 0; d < 16; ++d) {
    float s1 = wred64(sv2[d >> 1][d & 1]);
    float s2 = wred64(sq2[d >> 1][d & 1]);
    float m = s1 * inv_sr;
    mu[d] = m;
    float sg_ = fmaxf(s2 * inv_sr - m * m, 1e-30f);
    lsum += __logf(sg_);
  }
  const float cost = (16.f * bvv + lsum) * sum_r;
  const float aout = 1.0f / (1.0f + __expf(-lamv * (bav - cost)));

  if (mode == 2) {
    if (lane == 0) {
      float* ob = out + (size_t)(n * 544 + c * 16) * 36 + xx * 6 + y;
#pragma unroll
      for (int d = 0; d < 16; ++d) ob[d * 36] = mu[d];
      out[(size_t)(n * 544 + 512 + c) * 36 + xx * 6 + y] = aout;
    }
    return;
  }

  // ---- E phase: slice-staged (permuted taps); drain sPh during staging ----
  v2f nmu2[8];
#pragma unroll
  for (int d = 0; d < 8; ++d) { nmu2[d].x = -mu[2 * d]; nmu2[d].y = -mu[2 * d + 1]; }
  const float G = __logf(aout) - 0.5f * (lsum + 16.f * 1.8378770664093453f);

#pragma unroll
  for (int k = 0; k < 5; ++k) {
    __syncthreads();
    {
      const int tt = threadIdx.x;
      const int s = tt >> 7, o2 = (tt >> 2) & 31, q = tt & 3;
      const int ij = 2 * k + s;
      if (ij < 9) {
        const int i = ij / 3, j = ij - 3 * i;
        const int i2 = (i == 0) ? 0 : 3 - i;   // kperm = {0,2,1}
        const int j2 = (j == 0) ? 0 : 3 - j;
        const int pix = (2 * xx + i2) * 13 + (2 * y + j2);
        v4f v = *(const v4f*)(posT2 +
            ((size_t)((n * 169 + pix) * 32 + o2)) * 16 + q * 4);
        *(v4f*)(sPs + (s * 32 + o2) * 20 + q * 4) = v;
      }
      if (k > 0 && tt < 64) {                  // drain step k-1 (slots 0..7)
        const int slotd = 2 * (k - 1) + (tt >> 5), od = tt & 31;
        float sm = sPh[tt] + sPh[64 + tt] + sPh[128 + tt] + sPh[192 + tt];
        const int i = slotd / 3, j = slotd - 3 * i;
        atomicAdd(Dwrite + ((size_t)n * 169 + (2 * xx + i) * 13 + (2 * y + j)) * 32 + od, sm);
      }
    }
    __syncthreads();

    const int ijm = 2 * k + half;
    float ph = 0.f;
    if (ijm < 9) {
      const v4f* Pp = (const v4f*)(sPs + lane * 20);
      v4f P0 = Pp[0], P1 = Pp[1], P2 = Pp[2], P3 = Pp[3];
      const int i = ijm / 3, j = ijm - 3 * i;
      const int i2 = (i == 0) ? 0 : 3 - i;
      const int j2 = (j == 0) ? 0 : 3 - j;
      const v4f* Wp = (const v4f*)(wbase + ((i2 * 3 + j2) * 32 + o) * 16);
      v4f W0 = Wp[0], W1 = Wp[1], W2 = Wp[2], W3 = Wp[3];

      v2f PL0 = lo2(P0), PH0 = hi2(P0), PL1 = lo2(P1), PH1 = hi2(P1);
      v2f PL2 = lo2(P2), PH2 = hi2(P2), PL3 = lo2(P3), PH3 = hi2(P3);
      v2f ss2 = 0.f;
#pragma unroll
      for (int p = 0; p < 4; ++p) {
        v4f Wr = (p == 0) ? W0 : (p == 1) ? W1 : (p == 2) ? W2 : W3;
        v2f vlo = Wr.x * PL0 + Wr.y * PL1 + Wr.z * PL2 + Wr.w * PL3;
        v2f vhi = Wr.x * PH0 + Wr.y * PH1 + Wr.z * PH2 + Wr.w * PH3;
        v2f dlo = vlo + nmu2[p * 2 + 0];
        v2f dhi = vhi + nmu2[p * 2 + 1];
        ss2 += dlo * dlo;
        ss2 += dhi * dhi;
      }
      float ss = ss2.x + ss2.y;
      ph = __expf(G - ss);
      p_hat[((size_t)sg * 32 + c) * 288 + ijm * 32 + o] = ph;  // = base + lane + 64k
    }
    sPh[wave * 64 + lane] = ph;
  }
  // final drain: step 4, slot 8 (half 0 only; slot 9 contributed 0)
  __syncthreads();
  if (threadIdx.x < 32) {
    const int tt = threadIdx.x;
    float sm = sPh[tt] + sPh[64 + tt] + sPh[128 + tt] + sPh[192 + tt];
    atomicAdd(Dwrite + ((size_t)n * 169 + (2 * xx + 2) * 13 + (2 * y + 2)) * 32 + tt, sm);
  }
}

extern "C" void kernel_launch(void* const* d_in, const int* in_sizes, int n_in,
                              void* d_out, int out_size, void* d_ws,
                              size_t ws_size, hipStream_t stream) {
  const float* x   = (const float*)d_in[0];
  const float* Wt  = (const float*)d_in[1];
  const float* bv  = (const float*)d_in[2];
  const float* ba  = (const float*)d_in[3];
  const float* lam = (const float*)d_in[4];
  float* out = (float*)d_out;
  float* ws = (float*)d_ws;

  float* p_hat = ws + OFF_PHAT;
  float* D0    = ws + OFF_D0;
  float* D1    = ws + OFF_D1;
  float* posT2 = ws + OFF_POST;
  float* actT  = ws + OFF_ACTT;
  float* Wt2   = ws + OFF_WT2;

  (void)in_sizes; (void)n_in; (void)out_size; (void)ws_size;

  // fused prep: transposes + zero D0/D1 (D0,D1 contiguous in ws)
  prep_kernel<<<3787, 256, 0, stream>>>(x, Wt, posT2, actT, Wt2, D0);

  // M0 + E1 -> p_hat, D0
  em_kernel<<<2304, 256, 0, stream>>>(Wt2, posT2, actT, p_hat, D1, D0,
                                      bv, ba, lam, out, 0);
  // M1 (p_hat, D0) + E2 -> p_hat, D1
  em_kernel<<<2304, 256, 0, stream>>>(Wt2, posT2, actT, p_hat, D0, D1,
                                      bv, ba, lam, out, 1);
  // M2 (p_hat, D1) -> out
  em_kernel<<<2304, 256, 0, stream>>>(Wt2, posT2, actT, p_hat, D1, D0,
                                      bv, ba, lam, out, 2);
}

// Round 14
// 170.679 us; speedup vs baseline: 1.5284x; 1.5284x over previous
//
#include <hip/hip_runtime.h>

// ---------------------------------------------------------------------------
// ConvCaps (EM routing): b=8, B=32, C=32, K=3, stride=2, Win=13, Wout=6, 3 iters
// x: (8, 544, 13, 13) f32   [pose 512ch = (q,r,o), act 32ch]
// W: (3,3,32,32,4,4) f32    [ch=(ij*32+o)][c][p][q], 512 floats per ch
// out: (8, 544, 6, 6) f32
// vote[d=p*4+r] = sum_q W[ch][c][p][q] * pose[n,q,r,o, 2x+i, 2y+j]
//
// R14 = R10 (169.6us best) + votes register cache in E, at (256,2).
// Evidence: em pinned ~43.5us across 2-4 blocks/CU, 6-29KB LDS, packed or
// scalar (R7/R8/R10/R12/R13) -> occupancy-insensitive; only work reduction
// is left. E-phase vote recompute (10 loads + ~320 FMA) duplicates M's
// values exactly (kperm renames the slot, not the value) -> cache as
// v2f votes[5][8] (+80 VGPR, live ~145 < 256 cap at (256,2), no spill;
// R7 proved 2 blocks/CU == 4 blocks/CU perf).
// Session rules: cap < live set (256,3)/(256,5) -> spill; WRITE >> 13MB =
// spill signature; forced-asm packing -> scheduler regression.
// p_hat slices block-private; only D crosses blocks -> ping-pong D0/D1.
// ---------------------------------------------------------------------------

typedef float v2f __attribute__((ext_vector_type(2)));
typedef float v4f __attribute__((ext_vector_type(4)));

// workspace layout (floats)
#define OFF_PHAT 0           // 288*32*288 = 2654208   [spatial][c][slot]
#define OFF_D0   2654208     // 43264 = 8*169*32   [n][pix][o]
#define OFF_D1   2697472     // 43264
#define OFF_POST 2740736     // 692224 = 8*32*169*16   [(n,o)][pix][d]
#define OFF_ACTT 3432960     // 43264  [n][pix][o]
#define OFF_WT2  3476224     // 147456 = 32*288*16  [c][ch][d]
// total 3623680 floats = 14.5 MB

__device__ __forceinline__ float wred64(float v) {
#pragma unroll
  for (int m = 32; m >= 1; m >>= 1) v += __shfl_xor(v, m, 64);
  return v;
}

__device__ __forceinline__ v2f lo2(v4f a) { return __builtin_shufflevector(a, a, 0, 1); }
__device__ __forceinline__ v2f hi2(v4f a) { return __builtin_shufflevector(a, a, 2, 3); }

// One fused prep kernel (range-branched elementwise):
//   [0,692224)        pose transpose -> posT[((n*32+o)*169+pix)*16 + d]
//   [692224,735488)   act transpose  -> actT[n][pix][o]
//   [735488,882944)   W transpose    -> Wt2[c][ch][d]
//   [882944,969472)   zero D0 and D1
__global__ __launch_bounds__(256) void prep_kernel(
    const float* __restrict__ x, const float* __restrict__ Wt,
    float* __restrict__ posT, float* __restrict__ actT,
    float* __restrict__ Wt2, float* __restrict__ Dz) {
  int tid = blockIdx.x * 256 + threadIdx.x;   // 969472 = 3787*256
  if (tid < 692224) {
    int pix = tid % 169; int t = tid / 169;
    int o = t & 31; t >>= 5;
    int d = t & 15; int n = t >> 4;
    float v = x[((size_t)n * 544 + d * 32 + o) * 169 + pix];
    posT[((size_t)(n * 32 + o) * 169 + pix) * 16 + d] = v;
  } else if (tid < 735488) {
    int r = tid - 692224;
    int pix = r % 169; int t = r / 169;
    int o = t & 31; int n = t >> 5;
    float v = x[(size_t)n * 91936 + 86528 + o * 169 + pix];
    actT[((size_t)n * 169 + pix) * 32 + o] = v;
  } else if (tid < 882944) {
    int r = tid - 735488;                     // 147456 = 32*288*16
    int c = r / 4608; int s = r - c * 4608;
    int ch = s >> 4, d = s & 15;
    Wt2[r] = Wt[(size_t)ch * 512 + c * 16 + d];
  } else {
    Dz[tid - 882944] = 0.f;                   // D0 then D1 (contiguous)
  }
}

// Fused EM step.
// mode 0: M(uniform Rp) + E -> p_hat, Dwrite
// mode 1: M(p_hat, Dread) + E -> p_hat, Dwrite
// mode 2: M(p_hat, Dread) -> final output
__global__ __launch_bounds__(256, 2) void em_kernel(
    const float* __restrict__ Wt2, const float* __restrict__ posT,
    const float* __restrict__ actT, float* __restrict__ p_hat,
    const float* __restrict__ Dread, float* __restrict__ Dwrite,
    const float* __restrict__ beta_v, const float* __restrict__ beta_a,
    const float* __restrict__ lambda_, float* __restrict__ out, int mode) {
  __shared__ float sP[288 * 20];   // pose patch, stride 20 (float4-aligned)
  __shared__ float sE[288];        // a/1152 or a/D per child slot
  __shared__ float sPh[4 * 288];   // per-wave p_hat by slot, for D reduce

  const int g = blockIdx.x & 7;        // c group
  const int sg = blockIdx.x >> 3;      // spatial 0..287
  const int wave = threadIdx.x >> 6;
  const int lane = threadIdx.x & 63;
  const int c = g * 4 + wave;

  int t = sg;
  const int y = t % 6; t /= 6;
  const int xx = t % 6;
  const int n = t / 6;

  const float bvv = beta_v[0], bav = beta_a[0], lamv = lambda_[0];
  const float* wbase = Wt2 + (size_t)c * 4608;

  // ---- prefetch p_hat (global, coalesced) so vmcnt overlaps staging ----
  float phv[5];
  if (mode != 0) {
    const float* phb = p_hat + ((size_t)sg * 32 + c) * 288;
#pragma unroll
    for (int k = 0; k < 5; ++k) {
      int ch = lane + 64 * k; if (ch > 287) ch = 287;
      phv[k] = phb[ch];
    }
  }

  // ---- stage pose patch (coalesced float4) ----
  for (int task = threadIdx.x; task < 1152; task += 256) {
    int ch = task >> 2, q = task & 3;
    int o = ch & 31, ij = ch >> 5;
    int i = ij / 3, j = ij - i * 3;
    int pix = (2 * xx + i) * 13 + (2 * y + j);
    v4f v = *(const v4f*)(posT +
        ((size_t)((n * 32 + o) * 169) + pix) * 16 + q * 4);
    *(v4f*)(sP + ch * 20 + q * 4) = v;
  }
  // ---- stage rhat scale: a/1152 or a/D (32-contiguous reads) ----
  for (int task = threadIdx.x; task < 288; task += 256) {
    int o = task & 31, ij = task >> 5;
    int i = ij / 3, j = ij - i * 3;
    int idx = ((size_t)n * 169 + (2 * xx + i) * 13 + (2 * y + j)) * 32 + o;
    float a = actT[idx];
    sE[task] = (mode == 0) ? a * (1.0f / 1152.0f) : a / Dread[idx];
  }
  __syncthreads();

  // ---- M step: packed float2 accumulation; votes cached for E ----
  float sum_r = 0.f;
  v2f sv2[8], sq2[8];
  v2f votes[5][8];                 // +80 VGPR: E reuses these values
#pragma unroll
  for (int d = 0; d < 8; ++d) { sv2[d] = 0.f; sq2[d] = 0.f; }

#pragma unroll
  for (int k = 0; k < 5; ++k) {
    int ch = lane + 64 * k;
    const bool act_l = (ch < 288);
    const int chm = act_l ? ch : 0;

    const v4f* Pp = (const v4f*)(sP + chm * 20);
    v4f P0 = Pp[0], P1 = Pp[1], P2 = Pp[2], P3 = Pp[3];
    const v4f* Wp = (const v4f*)(wbase + chm * 16);
    v4f W0 = Wp[0], W1 = Wp[1], W2 = Wp[2], W3 = Wp[3];

    float rhat = sE[chm];
    if (mode != 0) rhat *= phv[k];
    if (!act_l) rhat = 0.f;
    sum_r += rhat;

    v2f PL0 = lo2(P0), PH0 = hi2(P0), PL1 = lo2(P1), PH1 = hi2(P1);
    v2f PL2 = lo2(P2), PH2 = hi2(P2), PL3 = lo2(P3), PH3 = hi2(P3);
    v2f r2 = rhat;

#pragma unroll
    for (int p = 0; p < 4; ++p) {
      v4f Wr = (p == 0) ? W0 : (p == 1) ? W1 : (p == 2) ? W2 : W3;
      v2f vlo = Wr.x * PL0 + Wr.y * PL1 + Wr.z * PL2 + Wr.w * PL3;
      v2f vhi = Wr.x * PH0 + Wr.y * PH1 + Wr.z * PH2 + Wr.w * PH3;
      votes[k][p * 2 + 0] = vlo;
      votes[k][p * 2 + 1] = vhi;
      v2f tlo = r2 * vlo, thi = r2 * vhi;
      sv2[p * 2 + 0] += tlo;
      sv2[p * 2 + 1] += thi;
      sq2[p * 2 + 0] += tlo * vlo;
      sq2[p * 2 + 1] += thi * vhi;
    }
  }

  sum_r = wred64(sum_r);
  const float inv_sr = 1.0f / sum_r;
  float mu[16];
  float lsum = 0.f;
#pragma unroll
  for (int d = 0; d < 16; ++d) {
    float s1 = wred64(sv2[d >> 1][d & 1]);
    float s2 = wred64(sq2[d >> 1][d & 1]);
    float m = s1 * inv_sr;
    mu[d] = m;
    float sg_ = fmaxf(s2 * inv_sr - m * m, 1e-30f);
    lsum += __logf(sg_);
  }
  const float cost = (16.f * bvv + lsum) * sum_r;
  const float aout = 1.0f / (1.0f + __expf(-lamv * (bav - cost)));

  if (mode == 2) {
    if (lane == 0) {
      float* ob = out + (size_t)(n * 544 + c * 16) * 36 + xx * 6 + y;
#pragma unroll
      for (int d = 0; d < 16; ++d) ob[d * 36] = mu[d];
      out[(size_t)(n * 544 + 512 + c) * 36 + xx * 6 + y] = aout;
    }
    return;
  }

  // ---- E step: reuse cached votes (no P/W reload, no vote recompute) ----
  v2f mu2[8];
#pragma unroll
  for (int d = 0; d < 8; ++d) { mu2[d].x = mu[2 * d]; mu2[d].y = mu[2 * d + 1]; }
  const float G = __logf(aout) - 0.5f * (lsum + 16.f * 1.8378770664093453f);

#pragma unroll
  for (int k = 0; k < 5; ++k) {
    int mch = lane + 64 * k;
    if (mch < 288) {
      v2f ss2 = 0.f;
#pragma unroll
      for (int d = 0; d < 8; ++d) {
        v2f dv = votes[k][d] - mu2[d];
        ss2 += dv * dv;
      }
      float ss = ss2.x + ss2.y;
      float ph = __expf(G - ss);
      int o = mch & 31, ijm = mch >> 5;
      int im = ijm / 3, jm = ijm - im * 3;
      int i2 = (im == 0) ? 0 : 3 - im;   // kperm = {0,2,1}, involution
      int j2 = (jm == 0) ? 0 : 3 - jm;
      int slot = (i2 * 3 + j2) * 32 + o;
      p_hat[((size_t)sg * 32 + c) * 288 + slot] = ph;
      sPh[wave * 288 + slot] = ph;
    }
  }
  __syncthreads();
  // D reduce over block's 4 c + global atomic (8 c-grp blocks contribute)
  for (int t2 = threadIdx.x; t2 < 288; t2 += 256) {
    float s = sPh[t2] + sPh[288 + t2] + sPh[576 + t2] + sPh[864 + t2];
    int o = t2 & 31, ij = t2 >> 5;
    int i = ij / 3, j = ij - i * 3;
    atomicAdd(Dwrite + ((size_t)n * 169 + (2 * xx + i) * 13 + (2 * y + j)) * 32 + o, s);
  }
}

extern "C" void kernel_launch(void* const* d_in, const int* in_sizes, int n_in,
                              void* d_out, int out_size, void* d_ws,
                              size_t ws_size, hipStream_t stream) {
  const float* x   = (const float*)d_in[0];
  const float* Wt  = (const float*)d_in[1];
  const float* bv  = (const float*)d_in[2];
  const float* ba  = (const float*)d_in[3];
  const float* lam = (const float*)d_in[4];
  float* out = (float*)d_out;
  float* ws = (float*)d_ws;

  float* p_hat = ws + OFF_PHAT;
  float* D0    = ws + OFF_D0;
  float* D1    = ws + OFF_D1;
  float* posT  = ws + OFF_POST;
  float* actT  = ws + OFF_ACTT;
  float* Wt2   = ws + OFF_WT2;

  (void)in_sizes; (void)n_in; (void)out_size; (void)ws_size;

  // fused prep: transposes + zero D0/D1 (D0,D1 contiguous in ws)
  prep_kernel<<<3787, 256, 0, stream>>>(x, Wt, posT, actT, Wt2, D0);

  // M0 + E1 -> p_hat, D0
  em_kernel<<<2304, 256, 0, stream>>>(Wt2, posT, actT, p_hat, D1, D0,
                                      bv, ba, lam, out, 0);
  // M1 (p_hat, D0) + E2 -> p_hat, D1
  em_kernel<<<2304, 256, 0, stream>>>(Wt2, posT, actT, p_hat, D0, D1,
                                      bv, ba, lam, out, 1);
  // M2 (p_hat, D1) -> out
  em_kernel<<<2304, 256, 0, stream>>>(Wt2, posT, actT, p_hat, D1, D0,
                                      bv, ba, lam, out, 2);
}